// Round 1
// 221.645 us; speedup vs baseline: 1.1367x; 1.1367x over previous
//
#include <hip/hip_runtime.h>

typedef unsigned short u16;
typedef unsigned int u32;
typedef float f32x4 __attribute__((ext_vector_type(4)));
typedef __bf16 bf16x8 __attribute__((ext_vector_type(8)));

#define N_TOK 4096
#define QKV_LD 1536
#define NH 4
#define HID 128
#define C_OUT 512

__device__ __forceinline__ float b2f(u16 u) { return __uint_as_float(((u32)u) << 16); }
__device__ __forceinline__ u16 f2b(float f) {
  u32 u = __float_as_uint(f);
  u32 r = (u + 0x7fffu + ((u >> 16) & 1u)) >> 16;
  return (u16)r;
}

// ---------------- batched tiled transpose: src[b][r][c] f32 -> dst[b][c][r] bf16
__global__ __launch_bounds__(256) void transpose_tile(
    const float* __restrict__ src, u16* __restrict__ dst, int R, int C)
{
  __shared__ u16 tile[32][33];
  const int b = blockIdx.z;
  const int c0 = blockIdx.x * 32, r0 = blockIdx.y * 32;
  const int tx = threadIdx.x & 31, ty = threadIdx.x >> 5;  // 32 x 8
  const float* s = src + (size_t)b * R * C;
  u16* d = dst + (size_t)b * R * C;
#pragma unroll
  for (int i = 0; i < 32; i += 8)
    tile[ty + i][tx] = f2b(s[(size_t)(r0 + ty + i) * C + c0 + tx]);
  __syncthreads();
#pragma unroll
  for (int i = 0; i < 32; i += 8)
    d[(size_t)(c0 + ty + i) * R + r0 + tx] = tile[tx][ty + i];
}

// ---------------- merged QKV weight transpose (3 tensors, 4 heads each) ----
__global__ __launch_bounds__(256) void transpose_qkv(
    const float* __restrict__ Wq, const float* __restrict__ Wk,
    const float* __restrict__ Wv, u16* __restrict__ dst)
{
  __shared__ u16 tile[32][33];
  const int z = blockIdx.z;                 // 0..11
  const int which = z >> 2, b = z & 3;
  const float* src = (which == 0) ? Wq : (which == 1) ? Wk : Wv;
  const int R = 512, C = 128;
  const int c0 = blockIdx.x * 32, r0 = blockIdx.y * 32;
  const int tx = threadIdx.x & 31, ty = threadIdx.x >> 5;
  const float* s = src + (size_t)b * R * C;
  u16* d = dst + (size_t)which * 4 * R * C + (size_t)b * R * C;
#pragma unroll
  for (int i = 0; i < 32; i += 8)
    tile[ty + i][tx] = f2b(s[(size_t)(r0 + ty + i) * C + c0 + tx]);
  __syncthreads();
#pragma unroll
  for (int i = 0; i < 32; i += 8)
    d[(size_t)(c0 + ty + i) * R + r0 + tx] = tile[tx][ty + i];
}

// ---------------- layernorm (optionally + relu), block per row, 4-wide -----
__global__ __launch_bounds__(256) void ln_kernel(
    const void* __restrict__ x, const float* __restrict__ g,
    const float* __restrict__ b, u16* __restrict__ y,
    int C, int in_f32, int do_relu)
{
  int row = blockIdx.x;
  int tid = threadIdx.x;
  const float* xf = (const float*)x + (size_t)row * C;
  const u16* xh = (const u16*)x + (size_t)row * C;
  float s1 = 0.f, s2 = 0.f;
  for (int c = tid * 4; c < C; c += 1024) {
    float4 v;
    if (in_f32) v = *(const float4*)(xf + c);
    else {
      uint2 u = *(const uint2*)(xh + c);
      v.x = b2f((u16)u.x); v.y = b2f((u16)(u.x >> 16));
      v.z = b2f((u16)u.y); v.w = b2f((u16)(u.y >> 16));
    }
    s1 += v.x + v.y + v.z + v.w;
    s2 += v.x * v.x + v.y * v.y + v.z * v.z + v.w * v.w;
  }
  __shared__ float red[2][4];
  for (int o = 32; o; o >>= 1) { s1 += __shfl_down(s1, o); s2 += __shfl_down(s2, o); }
  int lane = tid & 63, w = tid >> 6;
  if (lane == 0) { red[0][w] = s1; red[1][w] = s2; }
  __syncthreads();
  s1 = red[0][0] + red[0][1] + red[0][2] + red[0][3];
  s2 = red[1][0] + red[1][1] + red[1][2] + red[1][3];
  float mean = s1 / C;
  float var = s2 / C - mean * mean;
  float rs = rsqrtf(fmaxf(var, 0.f) + 1e-5f);
  u16* yr = y + (size_t)row * C;
  for (int c = tid * 4; c < C; c += 1024) {
    float4 v;
    if (in_f32) v = *(const float4*)(xf + c);
    else {
      uint2 u = *(const uint2*)(xh + c);
      v.x = b2f((u16)u.x); v.y = b2f((u16)(u.x >> 16));
      v.z = b2f((u16)u.y); v.w = b2f((u16)(u.y >> 16));
    }
    float4 gg = *(const float4*)(g + c);
    float4 bb = *(const float4*)(b + c);
    float o0 = (v.x - mean) * rs * gg.x + bb.x;
    float o1 = (v.y - mean) * rs * gg.y + bb.y;
    float o2 = (v.z - mean) * rs * gg.z + bb.z;
    float o3 = (v.w - mean) * rs * gg.w + bb.w;
    if (do_relu) {
      o0 = fmaxf(o0, 0.f); o1 = fmaxf(o1, 0.f);
      o2 = fmaxf(o2, 0.f); o3 = fmaxf(o3, 0.f);
    }
    u16 t[4] = {f2b(o0), f2b(o1), f2b(o2), f2b(o3)};
    *(uint2*)(yr + c) = *(const uint2*)t;
  }
}

// ---------------- 128x128-tile MFMA GEMM, 8 waves, reg-dbuf, split-K -------
#define LDK 40
__global__ __launch_bounds__(512, 4) void gemm128(
    const u16* __restrict__ A, int lda,
    const u16* __restrict__ Bt,
    void* __restrict__ C, int ldc, int outf32,
    const float* __restrict__ res,
    int Kslice, int Ktot, int bd, int atomic)
{
  __shared__ u16 As[128 * LDK];
  __shared__ u16 Bs[128 * LDK];
  const int bn = blockIdx.x, bm = blockIdx.y;
  const int m0 = bm * 128, n0 = bn * 128;
  const int kbase = blockIdx.z * Kslice;
  const int abase = (bd ? bn * Ktot : 0) + kbase;
  const int tid = threadIdx.x;
  const int lane = tid & 63, w = tid >> 6;
  const int wm = (w & 1) * 64;
  const int wn = (w >> 1) * 32;
  const int l16 = lane & 15, quad = lane >> 4;

  const int sr = tid >> 2, sc = (tid & 3) * 8;
  const u16* PA = A + (size_t)(m0 + sr) * lda + abase + sc;
  const u16* PB = Bt + (size_t)(n0 + sr) * Ktot + kbase + sc;

  f32x4 acc[4][2];
#pragma unroll
  for (int i = 0; i < 4; i++)
#pragma unroll
    for (int j = 0; j < 2; j++) acc[i][j] = (f32x4){0.f, 0.f, 0.f, 0.f};

  int4 pa = *(const int4*)PA;
  int4 pb = *(const int4*)PB;
  for (int kk = 0; kk < Kslice; kk += 32) {
    *(int4*)&As[sr * LDK + sc] = pa;
    *(int4*)&Bs[sr * LDK + sc] = pb;
    __syncthreads();
    if (kk + 32 < Kslice) {
      PA += 32; pa = *(const int4*)PA;
      PB += 32; pb = *(const int4*)PB;
    }
    bf16x8 af[4], bfr[2];
#pragma unroll
    for (int mt = 0; mt < 4; mt++)
      af[mt] = *(const bf16x8*)&As[(wm + mt * 16 + l16) * LDK + quad * 8];
#pragma unroll
    for (int nt = 0; nt < 2; nt++)
      bfr[nt] = *(const bf16x8*)&Bs[(wn + nt * 16 + l16) * LDK + quad * 8];
#pragma unroll
    for (int mt = 0; mt < 4; mt++)
#pragma unroll
      for (int nt = 0; nt < 2; nt++)
        acc[mt][nt] = __builtin_amdgcn_mfma_f32_16x16x32_bf16(
            af[mt], bfr[nt], acc[mt][nt], 0, 0, 0);
    __syncthreads();
  }

#pragma unroll
  for (int mt = 0; mt < 4; mt++)
#pragma unroll
    for (int nt = 0; nt < 2; nt++)
#pragma unroll
      for (int r = 0; r < 4; r++) {
        int gr = m0 + wm + mt * 16 + quad * 4 + r;
        int gc = n0 + wn + nt * 16 + l16;
        size_t off = (size_t)gr * ldc + gc;
        float v = acc[mt][nt][r];
        if (atomic) {
          atomicAdd((float*)C + off, v);
        } else {
          if (res) v += res[off];
          if (outf32) ((float*)C)[off] = v;
          else        ((u16*)C)[off] = f2b(v);
        }
      }
}

// ---------------- banded attention, MFMA QK^T + PV + fused Wo + residual ---
// Per block: 16 queries (i0..i0+15) x 1 head; band t in [0,112), j = i0-48+t.
// Fragment conventions mirrored from gemm128 (HW-validated rounds 6-7):
//   A[m][k]: lane m=l16 reads row m, cols quad*8..+8 (b128)
//   B[n][k]: lane n=l16 reads row n, same cols
//   C/D:     col = lane&15, row = quad*4+reg
#define TQ 16
#define BAND 112
#define KROW 136   // u16 row stride: 272B (16B-aligned), 68-word => 2-way-max b128 pattern
#define PROW 120   // f32 score row stride
__global__ __launch_bounds__(256) void attn_mfma(
    const u16* __restrict__ qkv, const float* __restrict__ pos,
    const float* __restrict__ ori, const int* __restrict__ batch,
    const u16* __restrict__ wot, const float* __restrict__ xres,
    float* __restrict__ out)
{
  const int h = blockIdx.y;
  const int i0 = blockIdx.x * TQ;
  const int j0 = i0 - 48;
  const int tid = threadIdx.x;
  const int lane = tid & 63, w = tid >> 6;
  const int l16 = lane & 15, quad = lane >> 4;

  __shared__ u16 kv[128 * KROW];   // K band [t<112][c]; then V^T [d<128][t<128]; then Wo_h [e][d]
  __shared__ u16 qp[TQ * KROW];    // Q tile [q][c]; then P bf16 [q][t<128]; then O bf16 [q][d]
  __shared__ float ps[TQ * PROW];  // f32 scores
  __shared__ float bpx[BAND], bpy[BAND], bpz[BAND];
  __shared__ float box_[BAND], boy_[BAND], boz_[BAND];
  __shared__ int bb[BAND];

  // ---- phase 1: stage geometry, K, Q ----
  for (int t = tid; t < BAND; t += 256) {
    int j = j0 + t;
    if (j >= 0 && j < N_TOK) {
      bpx[t] = pos[j * 3 + 0]; bpy[t] = pos[j * 3 + 1]; bpz[t] = pos[j * 3 + 2];
      box_[t] = ori[j * 3 + 0]; boy_[t] = ori[j * 3 + 1]; boz_[t] = ori[j * 3 + 2];
      bb[t] = batch[j];
    } else {
      bpx[t] = bpy[t] = bpz[t] = 0.f;
      box_[t] = boy_[t] = boz_[t] = 0.f;
      bb[t] = -12345;
    }
  }
  for (int idx = tid; idx < BAND * 16; idx += 256) {  // K: 112 x 128, 16B chunks
    int t = idx >> 4, c8 = (idx & 15) * 8;
    int j = j0 + t;
    int4 val = {0, 0, 0, 0};
    if (j >= 0 && j < N_TOK)
      val = *(const int4*)&qkv[(size_t)j * QKV_LD + 512 + h * HID + c8];
    *(int4*)&kv[t * KROW + c8] = val;
  }
  {  // Q: 16 x 128, one 16B chunk per thread
    int q = tid >> 4, c8 = (tid & 15) * 8;
    *(int4*)&qp[q * KROW + c8] =
        *(const int4*)&qkv[(size_t)(i0 + q) * QKV_LD + h * HID + c8];
  }
  __syncthreads();

  // ---- phase 2: scores S = Q K^T / sqrt(d) + gbias, masked -> ps ----
  {
    bf16x8 af[4];
#pragma unroll
    for (int kc = 0; kc < 4; kc++)
      af[kc] = *(const bf16x8*)&qp[l16 * KROW + kc * 32 + quad * 8];
#pragma unroll
    for (int ti = 0; ti < 2; ti++) {
      int tt = w + ti * 4;                 // key tile (7 tiles of 16)
      if (tt < 7) {
        f32x4 acc = (f32x4){0.f, 0.f, 0.f, 0.f};
#pragma unroll
        for (int kc = 0; kc < 4; kc++) {
          bf16x8 bf = *(const bf16x8*)&kv[(tt * 16 + l16) * KROW + kc * 32 + quad * 8];
          acc = __builtin_amdgcn_mfma_f32_16x16x32_bf16(af[kc], bf, acc, 0, 0, 0);
        }
        int t = tt * 16 + l16;
#pragma unroll
        for (int r = 0; r < 4; r++) {
          int q = quad * 4 + r, iq = q + 48;
          int dseq = iq - t;
          bool ok = (bb[t] == bb[iq]) && (dseq <= 48) && (dseq >= -48);
          {
#pragma clang fp contract(off)
            float dx = bpx[iq] - bpx[t], dy = bpy[iq] - bpy[t], dz = bpz[iq] - bpz[t];
            float d2 = dx * dx + dy * dy + dz * dz;
            ok = ok && (d2 <= 1.0f);
          }
          float s = -1e9f;
          if (ok) {
            float gb = box_[iq] * box_[t] + boy_[iq] * boy_[t] + boz_[iq] * boz_[t];
            s = acc[r] * 0.08838834764831845f + gb;
          }
          ps[q * PROW + t] = s;
        }
      }
    }
  }
  __syncthreads();

  // ---- phase 3: stage V^T (overwrites kv) + wave-parallel softmax -> P bf16 in qp ----
  for (int idx = tid; idx < BAND * 32; idx += 256) {  // V rows -> V^T cols
    int t = idx >> 5, d4 = (idx & 31) * 4;
    int j = j0 + t;
    uint2 val; val.x = 0; val.y = 0;
    if (j >= 0 && j < N_TOK)
      val = *(const uint2*)&qkv[(size_t)j * QKV_LD + 1024 + h * HID + d4];
    u16 e[4] = {(u16)val.x, (u16)(val.x >> 16), (u16)val.y, (u16)(val.y >> 16)};
#pragma unroll
    for (int jj = 0; jj < 4; jj++) {     // staggered write order: 16-way -> 4-way banks
      int dd = (jj + tid) & 3;
      kv[(d4 + dd) * KROW + t] = e[dd];
    }
  }
  for (int idx = tid; idx < 128 * 16; idx += 256) {  // zero pad cols t in [112,128)
    int d = idx >> 4, t = BAND + (idx & 15);
    kv[d * KROW + t] = 0;
  }
  {  // softmax: 16 lanes per row (rows 0..15), 7 elems per lane, shfl_xor reduce
    int row = tid >> 4, sub = tid & 15;
    float vals[7];
    float m = -1e30f;
#pragma unroll
    for (int i = 0; i < 7; i++) {
      vals[i] = ps[row * PROW + sub + i * 16];
      m = fmaxf(m, vals[i]);
    }
#pragma unroll
    for (int o = 8; o; o >>= 1) m = fmaxf(m, __shfl_xor(m, o));
    float s = 0.f;
#pragma unroll
    for (int i = 0; i < 7; i++) { vals[i] = __expf(vals[i] - m); s += vals[i]; }
#pragma unroll
    for (int o = 8; o; o >>= 1) s += __shfl_xor(s, o);
    float inv = 1.f / s;
#pragma unroll
    for (int i = 0; i < 7; i++)
      qp[row * KROW + sub + i * 16] = f2b(vals[i] * inv);
    qp[row * KROW + BAND + sub] = 0;   // pad t in [112,128)
  }
  __syncthreads();

  // ---- phase 5: O = P V via MFMA (A=P[q][t], B=V^T[d][t]) -> O bf16 regs ----
  u16 obuf[2][4];
  {
    bf16x8 paf[4];
#pragma unroll
    for (int kc = 0; kc < 4; kc++)
      paf[kc] = *(const bf16x8*)&qp[l16 * KROW + kc * 32 + quad * 8];
#pragma unroll
    for (int ti = 0; ti < 2; ti++) {
      int dt = w + ti * 4;                 // d tile (8 tiles of 16)
      f32x4 acc = (f32x4){0.f, 0.f, 0.f, 0.f};
#pragma unroll
      for (int kc = 0; kc < 4; kc++) {
        bf16x8 bf = *(const bf16x8*)&kv[(dt * 16 + l16) * KROW + kc * 32 + quad * 8];
        acc = __builtin_amdgcn_mfma_f32_16x16x32_bf16(paf[kc], bf, acc, 0, 0, 0);
      }
#pragma unroll
      for (int r = 0; r < 4; r++) obuf[ti][r] = f2b(acc[r]);
    }
  }
  __syncthreads();   // all reads of qp (P) and kv (V^T) complete

  // ---- phase 6: O -> qp [q][d]; stage Wo_h^T into kv [e][d] ----
#pragma unroll
  for (int ti = 0; ti < 2; ti++) {
    int dt = w + ti * 4;
#pragma unroll
    for (int r = 0; r < 4; r++)
      qp[(quad * 4 + r) * KROW + dt * 16 + l16] = obuf[ti][r];
  }
  {
    const u16* wsrc = wot + (size_t)h * HID * HID;
    for (int idx = tid; idx < 128 * 16; idx += 256) {
      int e = idx >> 4, c8 = (idx & 15) * 8;
      *(int4*)&kv[e * KROW + c8] = *(const int4*)&wsrc[e * HID + c8];
    }
  }
  __syncthreads();

  // ---- phase 7: out = O @ Wo_h + x (f32), A=O[q][d], B=Wo^T[e][d] ----
  {
    bf16x8 oaf[4];
#pragma unroll
    for (int kc = 0; kc < 4; kc++)
      oaf[kc] = *(const bf16x8*)&qp[l16 * KROW + kc * 32 + quad * 8];
#pragma unroll
    for (int ti = 0; ti < 2; ti++) {
      int et = w + ti * 4;                 // output col tile (8 tiles of 16)
      f32x4 acc = (f32x4){0.f, 0.f, 0.f, 0.f};
#pragma unroll
      for (int kc = 0; kc < 4; kc++) {
        bf16x8 bf = *(const bf16x8*)&kv[(et * 16 + l16) * KROW + kc * 32 + quad * 8];
        acc = __builtin_amdgcn_mfma_f32_16x16x32_bf16(oaf[kc], bf, acc, 0, 0, 0);
      }
#pragma unroll
      for (int r = 0; r < 4; r++) {
        int q = quad * 4 + r;
        size_t off = (size_t)(i0 + q) * C_OUT + h * HID + et * 16 + l16;
        out[off] = acc[r] + xres[off];
      }
    }
  }
}

// ---------------- launcher --------------------------------------------------
// Inputs f32, ints i32, OUTPUT f32. ws arena (24 MB), lifetime-aliased:
//   [0,4M)    xn -> x1n
//   [4,16M)   qkv  -> h[4,20M) after attn
//   [16,16.2M) Wot (read by fused attn)
//   [20,22M)  Btqkv -> W2t    [22,24M) W1t
//   x1 lives in d_out (f32); FFN2 atomically accumulates onto it.
#define MB (1048576)
extern "C" void kernel_launch(void* const* d_in, const int* in_sizes, int n_in,
                              void* d_out, int out_size, void* d_ws, size_t ws_size,
                              hipStream_t stream) {
  const float* x    = (const float*)d_in[0];
  const float* pos  = (const float*)d_in[1];
  const float* ori  = (const float*)d_in[2];
  const int*   batch = (const int*)d_in[4];
  const float* ln1g = (const float*)d_in[5];
  const float* ln1b = (const float*)d_in[6];
  const float* ln2g = (const float*)d_in[7];
  const float* ln2b = (const float*)d_in[8];
  const float* Wq = (const float*)d_in[9];
  const float* Wk = (const float*)d_in[10];
  const float* Wv = (const float*)d_in[11];
  const float* Wo = (const float*)d_in[12];
  const float* lnmg = (const float*)d_in[13];
  const float* lnmb = (const float*)d_in[14];
  const float* W1 = (const float*)d_in[15];
  const float* W2 = (const float*)d_in[16];
  float* out = (float*)d_out;

  char* ws = (char*)d_ws;
  u16* xn    = (u16*)(ws + 0);
  u16* x1n   = (u16*)(ws + 0);
  u16* qkv   = (u16*)(ws + 4 * MB);
  u16* h     = (u16*)(ws + 4 * MB);
  u16* Wot   = (u16*)(ws + 16 * MB);
  u16* Btqkv = (u16*)(ws + 20 * MB);
  u16* W2t   = (u16*)(ws + 20 * MB);
  u16* W1t   = (u16*)(ws + 22 * MB);

  // weight transposes -> K-contiguous bf16
  transpose_qkv<<<dim3(4, 16, 12), 256, 0, stream>>>(Wq, Wk, Wv, Btqkv);
  transpose_tile<<<dim3(64, 16, 1), 256, 0, stream>>>(W1, W1t, 512, 2048);

  // ln1
  ln_kernel<<<dim3(4096), 256, 0, stream>>>(x, ln1g, ln1b, xn, 512, 1, 0);
  // qkv = xn @ [Wq|Wk|Wv]
  gemm128<<<dim3(12, 32, 1), 512, 0, stream>>>(xn, 512, Btqkv, qkv, QKV_LD, 0,
                                               nullptr, 512, 512, 0, 0);
  transpose_tile<<<dim3(16, 64, 1), 256, 0, stream>>>(W2, W2t, 2048, 512);
  transpose_tile<<<dim3(4, 4, 4), 256, 0, stream>>>(Wo, Wot, 128, 128);

  // attention (MFMA) + fused Wo projection + residual -> out (f32)
  attn_mfma<<<dim3(256, NH), 256, 0, stream>>>(qkv, pos, ori, batch, Wot, x, out);

  // ln2
  ln_kernel<<<dim3(4096), 256, 0, stream>>>(out, ln2g, ln2b, x1n, 512, 1, 0);
  // h = x1n @ W1
  gemm128<<<dim3(16, 32, 1), 512, 0, stream>>>(x1n, 512, W1t, h, 2048, 0,
                                               nullptr, 512, 512, 0, 0);
  // h = relu(LN(h))
  ln_kernel<<<dim3(4096), 256, 0, stream>>>(h, lnmg, lnmb, h, 2048, 0, 1);
  // out += h @ W2  (split-K x4, atomic f32; out already holds x1)
  gemm128<<<dim3(4, 32, 4), 512, 0, stream>>>(h, 2048, W2t, out, 512, 1,
                                              nullptr, 512, 2048, 0, 1);
}

// Round 3
// 200.458 us; speedup vs baseline: 1.2568x; 1.1057x over previous
//
#include <hip/hip_runtime.h>

typedef unsigned short u16;
typedef unsigned int u32;
typedef float f32x4 __attribute__((ext_vector_type(4)));
typedef __bf16 bf16x8 __attribute__((ext_vector_type(8)));

#define N_TOK 4096
#define QKV_LD 1536
#define NH 4
#define HID 128
#define C_OUT 512

__device__ __forceinline__ float b2f(u16 u) { return __uint_as_float(((u32)u) << 16); }
__device__ __forceinline__ u16 f2b(float f) {
  u32 u = __float_as_uint(f);
  u32 r = (u + 0x7fffu + ((u >> 16) & 1u)) >> 16;
  return (u16)r;
}

// ---------------- batched tiled transpose: src[b][r][c] f32 -> dst[b][c][r] bf16
__global__ __launch_bounds__(256) void transpose_tile(
    const float* __restrict__ src, u16* __restrict__ dst, int R, int C)
{
  __shared__ u16 tile[32][33];
  const int b = blockIdx.z;
  const int c0 = blockIdx.x * 32, r0 = blockIdx.y * 32;
  const int tx = threadIdx.x & 31, ty = threadIdx.x >> 5;  // 32 x 8
  const float* s = src + (size_t)b * R * C;
  u16* d = dst + (size_t)b * R * C;
#pragma unroll
  for (int i = 0; i < 32; i += 8)
    tile[ty + i][tx] = f2b(s[(size_t)(r0 + ty + i) * C + c0 + tx]);
  __syncthreads();
#pragma unroll
  for (int i = 0; i < 32; i += 8)
    d[(size_t)(c0 + ty + i) * R + r0 + tx] = tile[tx][ty + i];
}

// ---------------- merged weight transpose: Wq/Wk/Wv + W1 + Wo in ONE launch -
// (W2 must NOT be here: W2t aliases Btqkv and is transposed only after the
//  QKV GEMM has consumed Btqkv.)
// flat block decode:
//   [0,1024)    W1  512x2048
//   [1024,1792) Wq/Wk/Wv  12 x 512x128
//   [1792,1856) Wo  4 x 128x128
__global__ __launch_bounds__(256) void transpose_all(
    const float* __restrict__ Wq, const float* __restrict__ Wk,
    const float* __restrict__ Wv, const float* __restrict__ Wo,
    const float* __restrict__ W1,
    u16* __restrict__ Btqkv, u16* __restrict__ Wot, u16* __restrict__ W1t)
{
  __shared__ u16 tile[32][33];
  const int idx = blockIdx.x;
  const float* s; u16* d; int R, C, r0, c0;
  if (idx < 1024) {                    // W1
    s = W1; d = W1t; R = 512; C = 2048;
    r0 = (idx >> 6) * 32; c0 = (idx & 63) * 32;
  } else if (idx < 1792) {             // Wq|Wk|Wv
    int i = idx - 1024;
    int z = i >> 6, rem = i & 63;
    int which = z >> 2, b = z & 3;
    const float* base = (which == 0) ? Wq : (which == 1) ? Wk : Wv;
    s = base + (size_t)b * 512 * 128;
    d = Btqkv + (size_t)which * 4 * 512 * 128 + (size_t)b * 512 * 128;
    R = 512; C = 128;
    r0 = (rem >> 2) * 32; c0 = (rem & 3) * 32;
  } else {                             // Wo
    int i = idx - 1792;
    int b = i >> 4, rem = i & 15;
    s = Wo + (size_t)b * 128 * 128;
    d = Wot + (size_t)b * 128 * 128;
    R = 128; C = 128;
    r0 = (rem >> 2) * 32; c0 = (rem & 3) * 32;
  }
  const int tx = threadIdx.x & 31, ty = threadIdx.x >> 5;  // 32 x 8
#pragma unroll
  for (int i = 0; i < 32; i += 8)
    tile[ty + i][tx] = f2b(s[(size_t)(r0 + ty + i) * C + c0 + tx]);
  __syncthreads();
#pragma unroll
  for (int i = 0; i < 32; i += 8)
    d[(size_t)(c0 + ty + i) * R + r0 + tx] = tile[tx][ty + i];
}

// ---------------- LN, C=512, f32 in: wave-per-row, register-resident -------
__global__ __launch_bounds__(256) void ln512_f32(
    const float* __restrict__ x, const float* __restrict__ g,
    const float* __restrict__ b, u16* __restrict__ y)
{
  const int lane = threadIdx.x & 63;
  const int row = blockIdx.x * 4 + (threadIdx.x >> 6);
  const float* xr = x + (size_t)row * 512;
  const int c = lane * 8;
  float4 a0 = *(const float4*)(xr + c);
  float4 a1 = *(const float4*)(xr + c + 4);
  float v[8] = {a0.x, a0.y, a0.z, a0.w, a1.x, a1.y, a1.z, a1.w};
  float s1 = 0.f, s2 = 0.f;
#pragma unroll
  for (int i = 0; i < 8; i++) { s1 += v[i]; s2 += v[i] * v[i]; }
#pragma unroll
  for (int o = 32; o; o >>= 1) { s1 += __shfl_xor(s1, o); s2 += __shfl_xor(s2, o); }
  float mean = s1 * (1.f / 512.f);
  float var = s2 * (1.f / 512.f) - mean * mean;
  float rs = rsqrtf(fmaxf(var, 0.f) + 1e-5f);
  float4 g0 = *(const float4*)(g + c), g1 = *(const float4*)(g + c + 4);
  float4 b0 = *(const float4*)(b + c), b1 = *(const float4*)(b + c + 4);
  float gg[8] = {g0.x, g0.y, g0.z, g0.w, g1.x, g1.y, g1.z, g1.w};
  float bb[8] = {b0.x, b0.y, b0.z, b0.w, b1.x, b1.y, b1.z, b1.w};
  u16 t[8];
#pragma unroll
  for (int i = 0; i < 8; i++) t[i] = f2b((v[i] - mean) * rs * gg[i] + bb[i]);
  *(uint4*)(y + (size_t)row * 512 + c) = *(const uint4*)t;
}

// ---------------- LN+ReLU, C=2048, bf16 in/out: block-per-row, 1 read ------
__global__ __launch_bounds__(256) void ln2048_bf16_relu(
    const u16* __restrict__ x, const float* __restrict__ g,
    const float* __restrict__ b, u16* __restrict__ y)
{
  const int row = blockIdx.x, tid = threadIdx.x;
  const int c = tid * 8;
  const u16* xr = x + (size_t)row * 2048;
  uint4 u = *(const uint4*)(xr + c);
  u16 e[8]; *(uint4*)e = u;
  float v[8];
#pragma unroll
  for (int i = 0; i < 8; i++) v[i] = b2f(e[i]);
  float s1 = 0.f, s2 = 0.f;
#pragma unroll
  for (int i = 0; i < 8; i++) { s1 += v[i]; s2 += v[i] * v[i]; }
#pragma unroll
  for (int o = 32; o; o >>= 1) { s1 += __shfl_xor(s1, o); s2 += __shfl_xor(s2, o); }
  __shared__ float red[2][4];
  int lane = tid & 63, w = tid >> 6;
  if (lane == 0) { red[0][w] = s1; red[1][w] = s2; }
  __syncthreads();
  s1 = red[0][0] + red[0][1] + red[0][2] + red[0][3];
  s2 = red[1][0] + red[1][1] + red[1][2] + red[1][3];
  float mean = s1 * (1.f / 2048.f);
  float var = s2 * (1.f / 2048.f) - mean * mean;
  float rs = rsqrtf(fmaxf(var, 0.f) + 1e-5f);
  float4 g0 = *(const float4*)(g + c), g1 = *(const float4*)(g + c + 4);
  float4 b0 = *(const float4*)(b + c), b1 = *(const float4*)(b + c + 4);
  float gg[8] = {g0.x, g0.y, g0.z, g0.w, g1.x, g1.y, g1.z, g1.w};
  float bb[8] = {b0.x, b0.y, b0.z, b0.w, b1.x, b1.y, b1.z, b1.w};
  u16 t[8];
#pragma unroll
  for (int i = 0; i < 8; i++)
    t[i] = f2b(fmaxf((v[i] - mean) * rs * gg[i] + bb[i], 0.f));
  *(uint4*)(y + (size_t)row * 2048 + c) = *(const uint4*)t;
}

// ---------------- 128x128-tile MFMA GEMM, 8 waves, reg-dbuf, split-K -------
#define LDK 40
__global__ __launch_bounds__(512, 4) void gemm128(
    const u16* __restrict__ A, int lda,
    const u16* __restrict__ Bt,
    void* __restrict__ C, int ldc, int outf32,
    const float* __restrict__ res,
    int Kslice, int Ktot, int bd, int atomic)
{
  __shared__ u16 As[128 * LDK];
  __shared__ u16 Bs[128 * LDK];
  const int bn = blockIdx.x, bm = blockIdx.y;
  const int m0 = bm * 128, n0 = bn * 128;
  const int kbase = blockIdx.z * Kslice;
  const int abase = (bd ? bn * Ktot : 0) + kbase;
  const int tid = threadIdx.x;
  const int lane = tid & 63, w = tid >> 6;
  const int wm = (w & 1) * 64;
  const int wn = (w >> 1) * 32;
  const int l16 = lane & 15, quad = lane >> 4;

  const int sr = tid >> 2, sc = (tid & 3) * 8;
  const u16* PA = A + (size_t)(m0 + sr) * lda + abase + sc;
  const u16* PB = Bt + (size_t)(n0 + sr) * Ktot + kbase + sc;

  f32x4 acc[4][2];
#pragma unroll
  for (int i = 0; i < 4; i++)
#pragma unroll
    for (int j = 0; j < 2; j++) acc[i][j] = (f32x4){0.f, 0.f, 0.f, 0.f};

  int4 pa = *(const int4*)PA;
  int4 pb = *(const int4*)PB;
  for (int kk = 0; kk < Kslice; kk += 32) {
    *(int4*)&As[sr * LDK + sc] = pa;
    *(int4*)&Bs[sr * LDK + sc] = pb;
    __syncthreads();
    if (kk + 32 < Kslice) {
      PA += 32; pa = *(const int4*)PA;
      PB += 32; pb = *(const int4*)PB;
    }
    bf16x8 af[4], bfr[2];
#pragma unroll
    for (int mt = 0; mt < 4; mt++)
      af[mt] = *(const bf16x8*)&As[(wm + mt * 16 + l16) * LDK + quad * 8];
#pragma unroll
    for (int nt = 0; nt < 2; nt++)
      bfr[nt] = *(const bf16x8*)&Bs[(wn + nt * 16 + l16) * LDK + quad * 8];
#pragma unroll
    for (int mt = 0; mt < 4; mt++)
#pragma unroll
      for (int nt = 0; nt < 2; nt++)
        acc[mt][nt] = __builtin_amdgcn_mfma_f32_16x16x32_bf16(
            af[mt], bfr[nt], acc[mt][nt], 0, 0, 0);
    __syncthreads();
  }

#pragma unroll
  for (int mt = 0; mt < 4; mt++)
#pragma unroll
    for (int nt = 0; nt < 2; nt++)
#pragma unroll
      for (int r = 0; r < 4; r++) {
        int gr = m0 + wm + mt * 16 + quad * 4 + r;
        int gc = n0 + wn + nt * 16 + l16;
        size_t off = (size_t)gr * ldc + gc;
        float v = acc[mt][nt][r];
        if (atomic) {
          atomicAdd((float*)C + off, v);
        } else {
          if (res) v += res[off];
          if (outf32) ((float*)C)[off] = v;
          else        ((u16*)C)[off] = f2b(v);
        }
      }
}

// ---------------- banded attention, MFMA QK^T + PV + fused Wo + residual ---
// Per block: 16 queries (i0..i0+15) x 1 head; band t in [0,112), j = i0-48+t.
// Fragment conventions mirrored from gemm128 (HW-validated rounds 6-7):
//   A[m][k]: lane m=l16 reads row m, cols quad*8..+8 (b128)
//   B[n][k]: lane n=l16 reads row n, same cols
//   C/D:     col = lane&15, row = quad*4+reg
#define TQ 16
#define BAND 112
#define KROW 136   // u16 row stride: 272B (16B-aligned), 68-word => 2-way-max b128 pattern
#define PROW 120   // f32 score row stride
__global__ __launch_bounds__(256) void attn_mfma(
    const u16* __restrict__ qkv, const float* __restrict__ pos,
    const float* __restrict__ ori, const int* __restrict__ batch,
    const u16* __restrict__ wot, const float* __restrict__ xres,
    float* __restrict__ out)
{
  const int h = blockIdx.y;
  // XCD-chunked bijective swizzle: gridDim.x=256, 8 XCDs -> each XCD owns a
  // contiguous 32-tile token range (consecutive tiles share 85% of K/V band).
  const int bxs = (blockIdx.x & 7) * 32 + (blockIdx.x >> 3);
  const int i0 = bxs * TQ;
  const int j0 = i0 - 48;
  const int tid = threadIdx.x;
  const int lane = tid & 63, w = tid >> 6;
  const int l16 = lane & 15, quad = lane >> 4;

  __shared__ u16 kv[128 * KROW];   // K band [t<112][c]; then V^T [d<128][t<128]; then Wo_h [e][d]
  __shared__ u16 qp[TQ * KROW];    // Q tile [q][c]; then P bf16 [q][t<128]; then O bf16 [q][d]
  __shared__ float ps[TQ * PROW];  // f32 scores
  __shared__ float bpx[BAND], bpy[BAND], bpz[BAND];
  __shared__ float box_[BAND], boy_[BAND], boz_[BAND];
  __shared__ int bb[BAND];

  // ---- phase 1: stage geometry, K, Q ----
  for (int t = tid; t < BAND; t += 256) {
    int j = j0 + t;
    if (j >= 0 && j < N_TOK) {
      bpx[t] = pos[j * 3 + 0]; bpy[t] = pos[j * 3 + 1]; bpz[t] = pos[j * 3 + 2];
      box_[t] = ori[j * 3 + 0]; boy_[t] = ori[j * 3 + 1]; boz_[t] = ori[j * 3 + 2];
      bb[t] = batch[j];
    } else {
      bpx[t] = bpy[t] = bpz[t] = 0.f;
      box_[t] = boy_[t] = boz_[t] = 0.f;
      bb[t] = -12345;
    }
  }
  for (int idx = tid; idx < BAND * 16; idx += 256) {  // K: 112 x 128, 16B chunks
    int t = idx >> 4, c8 = (idx & 15) * 8;
    int j = j0 + t;
    int4 val = {0, 0, 0, 0};
    if (j >= 0 && j < N_TOK)
      val = *(const int4*)&qkv[(size_t)j * QKV_LD + 512 + h * HID + c8];
    *(int4*)&kv[t * KROW + c8] = val;
  }
  {  // Q: 16 x 128, one 16B chunk per thread
    int q = tid >> 4, c8 = (tid & 15) * 8;
    *(int4*)&qp[q * KROW + c8] =
        *(const int4*)&qkv[(size_t)(i0 + q) * QKV_LD + h * HID + c8];
  }
  __syncthreads();

  // ---- phase 2: scores S = Q K^T / sqrt(d) + gbias, masked -> ps ----
  {
    bf16x8 af[4];
#pragma unroll
    for (int kc = 0; kc < 4; kc++)
      af[kc] = *(const bf16x8*)&qp[l16 * KROW + kc * 32 + quad * 8];
#pragma unroll
    for (int ti = 0; ti < 2; ti++) {
      int tt = w + ti * 4;                 // key tile (7 tiles of 16)
      if (tt < 7) {
        f32x4 acc = (f32x4){0.f, 0.f, 0.f, 0.f};
#pragma unroll
        for (int kc = 0; kc < 4; kc++) {
          bf16x8 bf = *(const bf16x8*)&kv[(tt * 16 + l16) * KROW + kc * 32 + quad * 8];
          acc = __builtin_amdgcn_mfma_f32_16x16x32_bf16(af[kc], bf, acc, 0, 0, 0);
        }
        int t = tt * 16 + l16;
#pragma unroll
        for (int r = 0; r < 4; r++) {
          int q = quad * 4 + r, iq = q + 48;
          int dseq = iq - t;
          bool ok = (bb[t] == bb[iq]) && (dseq <= 48) && (dseq >= -48);
          {
#pragma clang fp contract(off)
            float dx = bpx[iq] - bpx[t], dy = bpy[iq] - bpy[t], dz = bpz[iq] - bpz[t];
            float d2 = dx * dx + dy * dy + dz * dz;
            ok = ok && (d2 <= 1.0f);
          }
          float s = -1e9f;
          if (ok) {
            float gb = box_[iq] * box_[t] + boy_[iq] * boy_[t] + boz_[iq] * boz_[t];
            s = acc[r] * 0.08838834764831845f + gb;
          }
          ps[q * PROW + t] = s;
        }
      }
    }
  }
  __syncthreads();

  // ---- phase 3: stage V^T (overwrites kv) + wave-parallel softmax -> P bf16 in qp ----
  for (int idx = tid; idx < BAND * 32; idx += 256) {  // V rows -> V^T cols
    int t = idx >> 5, d4 = (idx & 31) * 4;
    int j = j0 + t;
    uint2 val; val.x = 0; val.y = 0;
    if (j >= 0 && j < N_TOK)
      val = *(const uint2*)&qkv[(size_t)j * QKV_LD + 1024 + h * HID + d4];
    u16 e[4] = {(u16)val.x, (u16)(val.x >> 16), (u16)val.y, (u16)(val.y >> 16)};
#pragma unroll
    for (int jj = 0; jj < 4; jj++) {     // staggered write order: 16-way -> 4-way banks
      int dd = (jj + tid) & 3;
      kv[(d4 + dd) * KROW + t] = e[dd];
    }
  }
  for (int idx = tid; idx < 128 * 16; idx += 256) {  // zero pad cols t in [112,128)
    int d = idx >> 4, t = BAND + (idx & 15);
    kv[d * KROW + t] = 0;
  }
  {  // softmax: 16 lanes per row (rows 0..15), 7 elems per lane, shfl_xor reduce
    int row = tid >> 4, sub = tid & 15;
    float vals[7];
    float m = -1e30f;
#pragma unroll
    for (int i = 0; i < 7; i++) {
      vals[i] = ps[row * PROW + sub + i * 16];
      m = fmaxf(m, vals[i]);
    }
#pragma unroll
    for (int o = 8; o; o >>= 1) m = fmaxf(m, __shfl_xor(m, o));
    float s = 0.f;
#pragma unroll
    for (int i = 0; i < 7; i++) { vals[i] = __expf(vals[i] - m); s += vals[i]; }
#pragma unroll
    for (int o = 8; o; o >>= 1) s += __shfl_xor(s, o);
    float inv = 1.f / s;
#pragma unroll
    for (int i = 0; i < 7; i++)
      qp[row * KROW + sub + i * 16] = f2b(vals[i] * inv);
    qp[row * KROW + BAND + sub] = 0;   // pad t in [112,128)
  }
  __syncthreads();

  // ---- phase 5: O = P V via MFMA (A=P[q][t], B=V^T[d][t]) -> O bf16 regs ----
  u16 obuf[2][4];
  {
    bf16x8 paf[4];
#pragma unroll
    for (int kc = 0; kc < 4; kc++)
      paf[kc] = *(const bf16x8*)&qp[l16 * KROW + kc * 32 + quad * 8];
#pragma unroll
    for (int ti = 0; ti < 2; ti++) {
      int dt = w + ti * 4;                 // d tile (8 tiles of 16)
      f32x4 acc = (f32x4){0.f, 0.f, 0.f, 0.f};
#pragma unroll
      for (int kc = 0; kc < 4; kc++) {
        bf16x8 bf = *(const bf16x8*)&kv[(dt * 16 + l16) * KROW + kc * 32 + quad * 8];
        acc = __builtin_amdgcn_mfma_f32_16x16x32_bf16(paf[kc], bf, acc, 0, 0, 0);
      }
#pragma unroll
      for (int r = 0; r < 4; r++) obuf[ti][r] = f2b(acc[r]);
    }
  }
  __syncthreads();   // all reads of qp (P) and kv (V^T) complete

  // ---- phase 6: O -> qp [q][d]; stage Wo_h^T into kv [e][d] ----
#pragma unroll
  for (int ti = 0; ti < 2; ti++) {
    int dt = w + ti * 4;
#pragma unroll
    for (int r = 0; r < 4; r++)
      qp[(quad * 4 + r) * KROW + dt * 16 + l16] = obuf[ti][r];
  }
  {
    const u16* wsrc = wot + (size_t)h * HID * HID;
    for (int idx = tid; idx < 128 * 16; idx += 256) {
      int e = idx >> 4, c8 = (idx & 15) * 8;
      *(int4*)&kv[e * KROW + c8] = *(const int4*)&wsrc[e * HID + c8];
    }
  }
  __syncthreads();

  // ---- phase 7: out = O @ Wo_h + x (f32), A=O[q][d], B=Wo^T[e][d] ----
  {
    bf16x8 oaf[4];
#pragma unroll
    for (int kc = 0; kc < 4; kc++)
      oaf[kc] = *(const bf16x8*)&qp[l16 * KROW + kc * 32 + quad * 8];
#pragma unroll
    for (int ti = 0; ti < 2; ti++) {
      int et = w + ti * 4;                 // output col tile (8 tiles of 16)
      f32x4 acc = (f32x4){0.f, 0.f, 0.f, 0.f};
#pragma unroll
      for (int kc = 0; kc < 4; kc++) {
        bf16x8 bf = *(const bf16x8*)&kv[(et * 16 + l16) * KROW + kc * 32 + quad * 8];
        acc = __builtin_amdgcn_mfma_f32_16x16x32_bf16(oaf[kc], bf, acc, 0, 0, 0);
      }
#pragma unroll
      for (int r = 0; r < 4; r++) {
        int q = quad * 4 + r;
        size_t off = (size_t)(i0 + q) * C_OUT + h * HID + et * 16 + l16;
        out[off] = acc[r] + xres[off];
      }
    }
  }
}

// ---------------- launcher --------------------------------------------------
// Inputs f32, ints i32, OUTPUT f32. ws arena (24 MB), lifetime-aliased:
//   [0,4M)    xn -> x1n
//   [4,16M)   qkv  -> h[4,20M) after attn
//   [16,16.2M) Wot (read by fused attn; dead before FFN1 writes h over it)
//   [20,22M)  Btqkv -> W2t (W2 transposed AFTER qkv GEMM consumes Btqkv)
//   [22,24M)  W1t
//   x1 lives in d_out (f32); FFN2 atomically accumulates onto it.
#define MB (1048576)
extern "C" void kernel_launch(void* const* d_in, const int* in_sizes, int n_in,
                              void* d_out, int out_size, void* d_ws, size_t ws_size,
                              hipStream_t stream) {
  const float* x    = (const float*)d_in[0];
  const float* pos  = (const float*)d_in[1];
  const float* ori  = (const float*)d_in[2];
  const int*   batch = (const int*)d_in[4];
  const float* ln1g = (const float*)d_in[5];
  const float* ln1b = (const float*)d_in[6];
  const float* ln2g = (const float*)d_in[7];
  const float* ln2b = (const float*)d_in[8];
  const float* Wq = (const float*)d_in[9];
  const float* Wk = (const float*)d_in[10];
  const float* Wv = (const float*)d_in[11];
  const float* Wo = (const float*)d_in[12];
  const float* lnmg = (const float*)d_in[13];
  const float* lnmb = (const float*)d_in[14];
  const float* W1 = (const float*)d_in[15];
  const float* W2 = (const float*)d_in[16];
  float* out = (float*)d_out;

  char* ws = (char*)d_ws;
  u16* xn    = (u16*)(ws + 0);
  u16* x1n   = (u16*)(ws + 0);
  u16* qkv   = (u16*)(ws + 4 * MB);
  u16* h     = (u16*)(ws + 4 * MB);
  u16* Wot   = (u16*)(ws + 16 * MB);
  u16* Btqkv = (u16*)(ws + 20 * MB);
  u16* W2t   = (u16*)(ws + 20 * MB);
  u16* W1t   = (u16*)(ws + 22 * MB);

  // weight transposes (all except W2, whose dst aliases Btqkv)
  transpose_all<<<dim3(1856), 256, 0, stream>>>(Wq, Wk, Wv, Wo, W1,
                                                Btqkv, Wot, W1t);
  // ln1
  ln512_f32<<<dim3(1024), 256, 0, stream>>>(x, ln1g, ln1b, xn);
  // qkv = xn @ [Wq|Wk|Wv]
  gemm128<<<dim3(12, 32, 1), 512, 0, stream>>>(xn, 512, Btqkv, qkv, QKV_LD, 0,
                                               nullptr, 512, 512, 0, 0);
  // W2 -> W2t (Btqkv now dead)
  transpose_tile<<<dim3(16, 64, 1), 256, 0, stream>>>(W2, W2t, 2048, 512);
  // attention (MFMA) + fused Wo projection + residual -> out (f32)
  attn_mfma<<<dim3(256, NH), 256, 0, stream>>>(qkv, pos, ori, batch, Wot, x, out);
  // ln2
  ln512_f32<<<dim3(1024), 256, 0, stream>>>(out, ln2g, ln2b, x1n);
  // h = x1n @ W1
  gemm128<<<dim3(16, 32, 1), 512, 0, stream>>>(x1n, 512, W1t, h, 2048, 0,
                                               nullptr, 512, 512, 0, 0);
  // h = relu(LN(h))
  ln2048_bf16_relu<<<dim3(4096), 256, 0, stream>>>(h, lnmg, lnmb, h);
  // out += h @ W2  (split-K x2, atomic f32; out already holds x1)
  gemm128<<<dim3(4, 32, 2), 512, 0, stream>>>(h, 2048, W2t, out, 512, 1,
                                              nullptr, 1024, 2048, 0, 1);
}

// Round 4
// 193.933 us; speedup vs baseline: 1.2991x; 1.0336x over previous
//
#include <hip/hip_runtime.h>

typedef unsigned short u16;
typedef unsigned int u32;
typedef float f32x4 __attribute__((ext_vector_type(4)));
typedef __bf16 bf16x8 __attribute__((ext_vector_type(8)));

#define N_TOK 4096
#define QKV_LD 1536
#define NH 4
#define HID 128
#define C_OUT 512

__device__ __forceinline__ float b2f(u16 u) { return __uint_as_float(((u32)u) << 16); }
__device__ __forceinline__ u16 f2b(float f) {
  u32 u = __float_as_uint(f);
  u32 r = (u + 0x7fffu + ((u >> 16) & 1u)) >> 16;
  return (u16)r;
}

// async global->LDS, 16B per lane; lptr must be wave-uniform (HW adds lane*16)
__device__ __forceinline__ void gload16(const u16* g, u16* l) {
  __builtin_amdgcn_global_load_lds(
      (const __attribute__((address_space(1))) void*)g,
      (__attribute__((address_space(3))) void*)l, 16, 0, 0);
}

// ---------------- 32x32 f32->bf16 transpose tile (shared device body) ------
__device__ __forceinline__ void tr32(const float* __restrict__ s,
                                     u16* __restrict__ d, int R, int C,
                                     int r0, int c0, u16 (*tile)[33]) {
  const int tx = threadIdx.x & 31, ty = threadIdx.x >> 5;  // 32 x 8
#pragma unroll
  for (int i = 0; i < 32; i += 8)
    tile[ty + i][tx] = f2b(s[(size_t)(r0 + ty + i) * C + c0 + tx]);
  __syncthreads();
#pragma unroll
  for (int i = 0; i < 32; i += 8)
    d[(size_t)(c0 + ty + i) * R + r0 + tx] = tile[tx][ty + i];
}

// ---------------- LN C=512 f32->bf16, wave-per-row (shared device body) ----
__device__ __forceinline__ void ln512_body(
    const float* __restrict__ x, const float* __restrict__ g,
    const float* __restrict__ b, u16* __restrict__ y, int row) {
  const int lane = threadIdx.x & 63;
  const float* xr = x + (size_t)row * 512;
  const int c = lane * 8;
  float4 a0 = *(const float4*)(xr + c);
  float4 a1 = *(const float4*)(xr + c + 4);
  float v[8] = {a0.x, a0.y, a0.z, a0.w, a1.x, a1.y, a1.z, a1.w};
  float s1 = 0.f, s2 = 0.f;
#pragma unroll
  for (int i = 0; i < 8; i++) { s1 += v[i]; s2 += v[i] * v[i]; }
#pragma unroll
  for (int o = 32; o; o >>= 1) { s1 += __shfl_xor(s1, o); s2 += __shfl_xor(s2, o); }
  float mean = s1 * (1.f / 512.f);
  float var = s2 * (1.f / 512.f) - mean * mean;
  float rs = rsqrtf(fmaxf(var, 0.f) + 1e-5f);
  float4 g0 = *(const float4*)(g + c), g1 = *(const float4*)(g + c + 4);
  float4 b0 = *(const float4*)(b + c), b1 = *(const float4*)(b + c + 4);
  float gg[8] = {g0.x, g0.y, g0.z, g0.w, g1.x, g1.y, g1.z, g1.w};
  float bb[8] = {b0.x, b0.y, b0.z, b0.w, b1.x, b1.y, b1.z, b1.w};
  u16 t[8];
#pragma unroll
  for (int i = 0; i < 8; i++) t[i] = f2b((v[i] - mean) * rs * gg[i] + bb[i]);
  *(uint4*)(y + (size_t)row * 512 + c) = *(const uint4*)t;
}

// ---------------- prep: ln1 + ALL first-phase weight transposes, ONE launch -
// block decode: [0,1024) ln1 (4 rows each); then transposes:
//   [1024,2048) W1 512x2048 ; [2048,2816) Wq/Wk/Wv 12x 512x128 ;
//   [2816,2880) Wo 4x 128x128
// (W2 is NOT here: W2t aliases Btqkv, transposed inside the attn launch.)
__global__ __launch_bounds__(256) void prep(
    const float* __restrict__ x, const float* __restrict__ ln1g,
    const float* __restrict__ ln1b, u16* __restrict__ xn,
    const float* __restrict__ Wq, const float* __restrict__ Wk,
    const float* __restrict__ Wv, const float* __restrict__ Wo,
    const float* __restrict__ W1,
    u16* __restrict__ Btqkv, u16* __restrict__ Wot, u16* __restrict__ W1t)
{
  __shared__ u16 tile[32][33];
  const int bid = blockIdx.x;
  if (bid < 1024) {
    ln512_body(x, ln1g, ln1b, xn, bid * 4 + (threadIdx.x >> 6));
    return;
  }
  const int idx = bid - 1024;
  const float* s; u16* d; int R, C, r0, c0;
  if (idx < 1024) {                    // W1
    s = W1; d = W1t; R = 512; C = 2048;
    r0 = (idx >> 6) * 32; c0 = (idx & 63) * 32;
  } else if (idx < 1792) {             // Wq|Wk|Wv
    int i = idx - 1024;
    int z = i >> 6, rem = i & 63;
    int which = z >> 2, b = z & 3;
    const float* base = (which == 0) ? Wq : (which == 1) ? Wk : Wv;
    s = base + (size_t)b * 512 * 128;
    d = Btqkv + (size_t)which * 4 * 512 * 128 + (size_t)b * 512 * 128;
    R = 512; C = 128;
    r0 = (rem >> 2) * 32; c0 = (rem & 3) * 32;
  } else {                             // Wo
    int i = idx - 1792;
    int b = i >> 4, rem = i & 15;
    s = Wo + (size_t)b * 128 * 128;
    d = Wot + (size_t)b * 128 * 128;
    R = 128; C = 128;
    r0 = (rem >> 2) * 32; c0 = (rem & 3) * 32;
  }
  tr32(s, d, R, C, r0, c0, tile);
}

// ---------------- LN, C=512, f32 in (standalone for ln2) -------------------
__global__ __launch_bounds__(256) void ln512_f32(
    const float* __restrict__ x, const float* __restrict__ g,
    const float* __restrict__ b, u16* __restrict__ y)
{
  ln512_body(x, g, b, y, blockIdx.x * 4 + (threadIdx.x >> 6));
}

// ---------------- LN+ReLU, C=2048, bf16 in/out: block-per-row, 1 read ------
__global__ __launch_bounds__(256) void ln2048_bf16_relu(
    const u16* __restrict__ x, const float* __restrict__ g,
    const float* __restrict__ b, u16* __restrict__ y)
{
  const int row = blockIdx.x, tid = threadIdx.x;
  const int c = tid * 8;
  const u16* xr = x + (size_t)row * 2048;
  uint4 u = *(const uint4*)(xr + c);
  u16 e[8]; *(uint4*)e = u;
  float v[8];
#pragma unroll
  for (int i = 0; i < 8; i++) v[i] = b2f(e[i]);
  float s1 = 0.f, s2 = 0.f;
#pragma unroll
  for (int i = 0; i < 8; i++) { s1 += v[i]; s2 += v[i] * v[i]; }
#pragma unroll
  for (int o = 32; o; o >>= 1) { s1 += __shfl_xor(s1, o); s2 += __shfl_xor(s2, o); }
  __shared__ float red[2][4];
  int lane = tid & 63, w = tid >> 6;
  if (lane == 0) { red[0][w] = s1; red[1][w] = s2; }
  __syncthreads();
  s1 = red[0][0] + red[0][1] + red[0][2] + red[0][3];
  s2 = red[1][0] + red[1][1] + red[1][2] + red[1][3];
  float mean = s1 * (1.f / 2048.f);
  float var = s2 * (1.f / 2048.f) - mean * mean;
  float rs = rsqrtf(fmaxf(var, 0.f) + 1e-5f);
  float4 g0 = *(const float4*)(g + c), g1 = *(const float4*)(g + c + 4);
  float4 b0 = *(const float4*)(b + c), b1 = *(const float4*)(b + c + 4);
  float gg[8] = {g0.x, g0.y, g0.z, g0.w, g1.x, g1.y, g1.z, g1.w};
  float bb[8] = {b0.x, b0.y, b0.z, b0.w, b1.x, b1.y, b1.z, b1.w};
  u16 t[8];
#pragma unroll
  for (int i = 0; i < 8; i++)
    t[i] = f2b(fmaxf((v[i] - mean) * rs * gg[i] + bb[i], 0.f));
  *(uint4*)(y + (size_t)row * 2048 + c) = *(const uint4*)t;
}

// ---------------- 128x128-tile MFMA GEMM, 8 waves, global_load_lds ---------
// LDS linear [128][32] u16 per buffer (gload_lds needs linear dest).
// XOR-swizzle pair (rule 21: both-sides-or-neither):
//   stage: lane (w,l) -> LDS row r=tid>>2, slot s=tid&3; global src chunk
//          c = s ^ ((tid>>3)&3)   (inverse-swizzled SOURCE, LDS stays linear)
//   read:  row R, chunk q -> slot q ^ ((R>>1)&3)  (2-way banks = free)
__global__ __launch_bounds__(512, 4) void gemm128(
    const u16* __restrict__ A, int lda,
    const u16* __restrict__ Bt,
    void* __restrict__ C, int ldc, int outf32,
    const float* __restrict__ res,
    int Kslice, int Ktot, int atomic)
{
  __shared__ u16 As[2][128 * 32];
  __shared__ u16 Bs[2][128 * 32];
  const int bn = blockIdx.x, bm = blockIdx.y;
  const int m0 = bm * 128, n0 = bn * 128;
  const int kbase = blockIdx.z * Kslice;
  const int tid = threadIdx.x;
  const int lane = tid & 63, w = tid >> 6;
  const int wm = (w & 1) * 64;
  const int wn = (w >> 1) * 32;
  const int l16 = lane & 15, quad = lane >> 4;

  // staging addresses (per-lane global, wave-uniform LDS base)
  const int r_st = tid >> 2;                       // LDS row 0..127
  const int chunk = (tid & 3) ^ ((tid >> 3) & 3);  // inverse-swizzled src chunk
  const u16* PA = A + (size_t)(m0 + r_st) * lda + kbase + chunk * 8;
  const u16* PB = Bt + (size_t)(n0 + r_st) * Ktot + kbase + chunk * 8;
  const int wbase = w * 512;                       // wave's 1KB LDS slice

  // fragment-read slot swizzle (lane-only dependent)
  const int slot8 = (quad ^ ((l16 >> 1) & 3)) * 8;

  f32x4 acc[4][2];
#pragma unroll
  for (int i = 0; i < 4; i++)
#pragma unroll
    for (int j = 0; j < 2; j++) acc[i][j] = (f32x4){0.f, 0.f, 0.f, 0.f};

  gload16(PA, &As[0][wbase]);
  gload16(PB, &Bs[0][wbase]);
  __syncthreads();

  int buf = 0;
  for (int kk = 0; kk < Kslice; kk += 32) {
    if (kk + 32 < Kslice) {          // stage next tile while computing this
      PA += 32; PB += 32;
      gload16(PA, &As[buf ^ 1][wbase]);
      gload16(PB, &Bs[buf ^ 1][wbase]);
    }
    bf16x8 af[4], bfr[2];
#pragma unroll
    for (int mt = 0; mt < 4; mt++)
      af[mt] = *(const bf16x8*)&As[buf][(wm + mt * 16 + l16) * 32 + slot8];
#pragma unroll
    for (int nt = 0; nt < 2; nt++)
      bfr[nt] = *(const bf16x8*)&Bs[buf][(wn + nt * 16 + l16) * 32 + slot8];
#pragma unroll
    for (int mt = 0; mt < 4; mt++)
#pragma unroll
      for (int nt = 0; nt < 2; nt++)
        acc[mt][nt] = __builtin_amdgcn_mfma_f32_16x16x32_bf16(
            af[mt], bfr[nt], acc[mt][nt], 0, 0, 0);
    __syncthreads();   // drains vmcnt (stage done) + lgkm; guards buf reuse
    buf ^= 1;
  }

#pragma unroll
  for (int mt = 0; mt < 4; mt++)
#pragma unroll
    for (int nt = 0; nt < 2; nt++)
#pragma unroll
      for (int r = 0; r < 4; r++) {
        int gr = m0 + wm + mt * 16 + quad * 4 + r;
        int gc = n0 + wn + nt * 16 + l16;
        size_t off = (size_t)gr * ldc + gc;
        float v = acc[mt][nt][r];
        if (atomic) {
          atomicAdd((float*)C + off, v);
        } else {
          if (res) v += res[off];
          if (outf32) ((float*)C)[off] = v;
          else        ((u16*)C)[off] = f2b(v);
        }
      }
}

// ---------------- banded attention + fused Wo + residual (+W2 transpose) ---
// blockIdx.x < 256: attention for 16 queries x 1 head.
// blockIdx.x >= 256: one 32x32 W2-transpose tile (Btqkv dead by now).
#define TQ 16
#define BAND 112
#define KROW 136   // u16 row stride: 272B, 68-word => 2-way-max b128 pattern
#define PROW 120   // f32 score row stride
__global__ __launch_bounds__(256) void attn_mfma(
    const u16* __restrict__ qkv, const float* __restrict__ pos,
    const float* __restrict__ ori, const int* __restrict__ batch,
    const u16* __restrict__ wot, const float* __restrict__ xres,
    float* __restrict__ out,
    const float* __restrict__ W2, u16* __restrict__ W2t)
{
  __shared__ u16 kv[128 * KROW];   // K band; then V^T; then Wo_h (or tr tile)
  __shared__ u16 qp[TQ * KROW];    // Q tile; then P bf16; then O bf16
  __shared__ float ps[TQ * PROW];  // f32 scores
  __shared__ float bpx[BAND], bpy[BAND], bpz[BAND];
  __shared__ float box_[BAND], boy_[BAND], boz_[BAND];
  __shared__ int bb[BAND];

  if (blockIdx.x >= 256) {         // ---- W2 transpose tile (2048x512) ----
    int idx = (blockIdx.x - 256) + blockIdx.y * 256;   // 0..1023
    int r0 = (idx >> 4) * 32, c0 = (idx & 15) * 32;
    tr32(W2, W2t, 2048, 512, r0, c0, (u16(*)[33])kv);
    return;
  }

  const int h = blockIdx.y;
  // XCD-chunked bijective swizzle over the 256 attn blocks
  const int bxs = (blockIdx.x & 7) * 32 + (blockIdx.x >> 3);
  const int i0 = bxs * TQ;
  const int j0 = i0 - 48;
  const int tid = threadIdx.x;
  const int lane = tid & 63, w = tid >> 6;
  const int l16 = lane & 15, quad = lane >> 4;

  // ---- phase 1: stage geometry, K, Q ----
  for (int t = tid; t < BAND; t += 256) {
    int j = j0 + t;
    if (j >= 0 && j < N_TOK) {
      bpx[t] = pos[j * 3 + 0]; bpy[t] = pos[j * 3 + 1]; bpz[t] = pos[j * 3 + 2];
      box_[t] = ori[j * 3 + 0]; boy_[t] = ori[j * 3 + 1]; boz_[t] = ori[j * 3 + 2];
      bb[t] = batch[j];
    } else {
      bpx[t] = bpy[t] = bpz[t] = 0.f;
      box_[t] = boy_[t] = boz_[t] = 0.f;
      bb[t] = -12345;
    }
  }
  for (int idx = tid; idx < BAND * 16; idx += 256) {  // K: 112 x 128
    int t = idx >> 4, c8 = (idx & 15) * 8;
    int j = j0 + t;
    int4 val = {0, 0, 0, 0};
    if (j >= 0 && j < N_TOK)
      val = *(const int4*)&qkv[(size_t)j * QKV_LD + 512 + h * HID + c8];
    *(int4*)&kv[t * KROW + c8] = val;
  }
  {  // Q: 16 x 128
    int q = tid >> 4, c8 = (tid & 15) * 8;
    *(int4*)&qp[q * KROW + c8] =
        *(const int4*)&qkv[(size_t)(i0 + q) * QKV_LD + h * HID + c8];
  }
  __syncthreads();

  // ---- phase 2: scores S = Q K^T / sqrt(d) + gbias, masked -> ps ----
  {
    bf16x8 af[4];
#pragma unroll
    for (int kc = 0; kc < 4; kc++)
      af[kc] = *(const bf16x8*)&qp[l16 * KROW + kc * 32 + quad * 8];
#pragma unroll
    for (int ti = 0; ti < 2; ti++) {
      int tt = w + ti * 4;                 // key tile (7 tiles of 16)
      if (tt < 7) {
        f32x4 acc = (f32x4){0.f, 0.f, 0.f, 0.f};
#pragma unroll
        for (int kc = 0; kc < 4; kc++) {
          bf16x8 bf = *(const bf16x8*)&kv[(tt * 16 + l16) * KROW + kc * 32 + quad * 8];
          acc = __builtin_amdgcn_mfma_f32_16x16x32_bf16(af[kc], bf, acc, 0, 0, 0);
        }
        int t = tt * 16 + l16;
#pragma unroll
        for (int r = 0; r < 4; r++) {
          int q = quad * 4 + r, iq = q + 48;
          int dseq = iq - t;
          bool ok = (bb[t] == bb[iq]) && (dseq <= 48) && (dseq >= -48);
          {
#pragma clang fp contract(off)
            float dx = bpx[iq] - bpx[t], dy = bpy[iq] - bpy[t], dz = bpz[iq] - bpz[t];
            float d2 = dx * dx + dy * dy + dz * dz;
            ok = ok && (d2 <= 1.0f);
          }
          float s = -1e9f;
          if (ok) {
            float gb = box_[iq] * box_[t] + boy_[iq] * boy_[t] + boz_[iq] * boz_[t];
            s = acc[r] * 0.08838834764831845f + gb;
          }
          ps[q * PROW + t] = s;
        }
      }
    }
  }
  __syncthreads();

  // ---- phase 3: stage V^T (overwrites kv) + wave-parallel softmax ----
  for (int idx = tid; idx < BAND * 32; idx += 256) {  // V rows -> V^T cols
    int t = idx >> 5, d4 = (idx & 31) * 4;
    int j = j0 + t;
    uint2 val; val.x = 0; val.y = 0;
    if (j >= 0 && j < N_TOK)
      val = *(const uint2*)&qkv[(size_t)j * QKV_LD + 1024 + h * HID + d4];
    u16 e[4] = {(u16)val.x, (u16)(val.x >> 16), (u16)val.y, (u16)(val.y >> 16)};
#pragma unroll
    for (int jj = 0; jj < 4; jj++) {     // staggered write order
      int dd = (jj + tid) & 3;
      kv[(d4 + dd) * KROW + t] = e[dd];
    }
  }
  for (int idx = tid; idx < 128 * 16; idx += 256) {  // zero pad t in [112,128)
    int d = idx >> 4, t = BAND + (idx & 15);
    kv[d * KROW + t] = 0;
  }
  {  // softmax: 16 lanes per row, 7 elems per lane, shfl_xor reduce
    int row = tid >> 4, sub = tid & 15;
    float vals[7];
    float m = -1e30f;
#pragma unroll
    for (int i = 0; i < 7; i++) {
      vals[i] = ps[row * PROW + sub + i * 16];
      m = fmaxf(m, vals[i]);
    }
#pragma unroll
    for (int o = 8; o; o >>= 1) m = fmaxf(m, __shfl_xor(m, o));
    float s = 0.f;
#pragma unroll
    for (int i = 0; i < 7; i++) { vals[i] = __expf(vals[i] - m); s += vals[i]; }
#pragma unroll
    for (int o = 8; o; o >>= 1) s += __shfl_xor(s, o);
    float inv = 1.f / s;
#pragma unroll
    for (int i = 0; i < 7; i++)
      qp[row * KROW + sub + i * 16] = f2b(vals[i] * inv);
    qp[row * KROW + BAND + sub] = 0;
  }
  __syncthreads();

  // ---- phase 5: O = P V via MFMA -> O bf16 regs ----
  u16 obuf[2][4];
  {
    bf16x8 paf[4];
#pragma unroll
    for (int kc = 0; kc < 4; kc++)
      paf[kc] = *(const bf16x8*)&qp[l16 * KROW + kc * 32 + quad * 8];
#pragma unroll
    for (int ti = 0; ti < 2; ti++) {
      int dt = w + ti * 4;
      f32x4 acc = (f32x4){0.f, 0.f, 0.f, 0.f};
#pragma unroll
      for (int kc = 0; kc < 4; kc++) {
        bf16x8 bf = *(const bf16x8*)&kv[(dt * 16 + l16) * KROW + kc * 32 + quad * 8];
        acc = __builtin_amdgcn_mfma_f32_16x16x32_bf16(paf[kc], bf, acc, 0, 0, 0);
      }
#pragma unroll
      for (int r = 0; r < 4; r++) obuf[ti][r] = f2b(acc[r]);
    }
  }
  __syncthreads();

  // ---- phase 6: O -> qp [q][d]; stage Wo_h^T into kv [e][d] ----
#pragma unroll
  for (int ti = 0; ti < 2; ti++) {
    int dt = w + ti * 4;
#pragma unroll
    for (int r = 0; r < 4; r++)
      qp[(quad * 4 + r) * KROW + dt * 16 + l16] = obuf[ti][r];
  }
  {
    const u16* wsrc = wot + (size_t)h * HID * HID;
    for (int idx = tid; idx < 128 * 16; idx += 256) {
      int e = idx >> 4, c8 = (idx & 15) * 8;
      *(int4*)&kv[e * KROW + c8] = *(const int4*)&wsrc[e * HID + c8];
    }
  }
  __syncthreads();

  // ---- phase 7: out = O @ Wo_h + x (f32) ----
  {
    bf16x8 oaf[4];
#pragma unroll
    for (int kc = 0; kc < 4; kc++)
      oaf[kc] = *(const bf16x8*)&qp[l16 * KROW + kc * 32 + quad * 8];
#pragma unroll
    for (int ti = 0; ti < 2; ti++) {
      int et = w + ti * 4;
      f32x4 acc = (f32x4){0.f, 0.f, 0.f, 0.f};
#pragma unroll
      for (int kc = 0; kc < 4; kc++) {
        bf16x8 bf = *(const bf16x8*)&kv[(et * 16 + l16) * KROW + kc * 32 + quad * 8];
        acc = __builtin_amdgcn_mfma_f32_16x16x32_bf16(oaf[kc], bf, acc, 0, 0, 0);
      }
#pragma unroll
      for (int r = 0; r < 4; r++) {
        int q = quad * 4 + r;
        size_t off = (size_t)(i0 + q) * C_OUT + h * HID + et * 16 + l16;
        out[off] = acc[r] + xres[off];
      }
    }
  }
}

// ---------------- launcher --------------------------------------------------
// 7 dispatches. ws arena (24 MB), lifetime-aliased:
//   [0,4M)    xn -> x1n
//   [4,16M)   qkv  -> h[4,20M) after attn
//   [16,16.2M) Wot (read by fused attn; dead before FFN1 writes h over it)
//   [20,22M)  Btqkv -> W2t (W2 transposed inside attn launch, after QKV GEMM)
//   [22,24M)  W1t
//   x1 lives in d_out (f32); FFN2 atomically accumulates onto it.
#define MB (1048576)
extern "C" void kernel_launch(void* const* d_in, const int* in_sizes, int n_in,
                              void* d_out, int out_size, void* d_ws, size_t ws_size,
                              hipStream_t stream) {
  const float* x    = (const float*)d_in[0];
  const float* pos  = (const float*)d_in[1];
  const float* ori  = (const float*)d_in[2];
  const int*   batch = (const int*)d_in[4];
  const float* ln1g = (const float*)d_in[5];
  const float* ln1b = (const float*)d_in[6];
  const float* ln2g = (const float*)d_in[7];
  const float* ln2b = (const float*)d_in[8];
  const float* Wq = (const float*)d_in[9];
  const float* Wk = (const float*)d_in[10];
  const float* Wv = (const float*)d_in[11];
  const float* Wo = (const float*)d_in[12];
  const float* lnmg = (const float*)d_in[13];
  const float* lnmb = (const float*)d_in[14];
  const float* W1 = (const float*)d_in[15];
  const float* W2 = (const float*)d_in[16];
  float* out = (float*)d_out;

  char* ws = (char*)d_ws;
  u16* xn    = (u16*)(ws + 0);
  u16* x1n   = (u16*)(ws + 0);
  u16* qkv   = (u16*)(ws + 4 * MB);
  u16* h     = (u16*)(ws + 4 * MB);
  u16* Wot   = (u16*)(ws + 16 * MB);
  u16* Btqkv = (u16*)(ws + 20 * MB);
  u16* W2t   = (u16*)(ws + 20 * MB);
  u16* W1t   = (u16*)(ws + 22 * MB);

  // 1. ln1 + all first-phase weight transposes
  prep<<<dim3(2880), 256, 0, stream>>>(x, ln1g, ln1b, xn,
                                       Wq, Wk, Wv, Wo, W1, Btqkv, Wot, W1t);
  // 2. qkv = xn @ [Wq|Wk|Wv]
  gemm128<<<dim3(12, 32, 1), 512, 0, stream>>>(xn, 512, Btqkv, qkv, QKV_LD, 0,
                                               nullptr, 512, 512, 0);
  // 3. attention + fused Wo + residual -> out (f32); plus W2->W2t transpose
  attn_mfma<<<dim3(512, NH), 256, 0, stream>>>(qkv, pos, ori, batch, Wot, x, out,
                                               W2, W2t);
  // 4. ln2
  ln512_f32<<<dim3(1024), 256, 0, stream>>>(out, ln2g, ln2b, x1n);
  // 5. h = x1n @ W1
  gemm128<<<dim3(16, 32, 1), 512, 0, stream>>>(x1n, 512, W1t, h, 2048, 0,
                                               nullptr, 512, 512, 0);
  // 6. h = relu(LN(h))
  ln2048_bf16_relu<<<dim3(4096), 256, 0, stream>>>(h, lnmg, lnmb, h);
  // 7. out += h @ W2  (split-K x2, atomic f32; out already holds x1)
  gemm128<<<dim3(4, 32, 2), 512, 0, stream>>>(h, 2048, W2t, out, 512, 1,
                                              nullptr, 1024, 2048, 1);
}